// Round 10
// baseline (729.904 us; speedup 1.0000x reference)
//
#include <hip/hip_runtime.h>
#include <math.h>

// ConvGRU v9: 2 timesteps per kernel via halo pyramid (32 launches).
// x: (4,16,64,64,64) f32, Wx: (96,16,3,3), bx: (96), Wh: (96,32,3,3).
// r-gate dead -> M = 32 oc x 2 gates; K = 48 cin x 12 (9 taps + 3 phantoms)
// = 576 = 36 chunks of 16 (c<12: x cins, c>=12: h cins).
// Block (b,y), 8 waves. Kernel s handles t0=2s, t0+1:
//   stage h^{t0} rows y-2..y+2 (planeA) + x(t0) rows y-2..y+2 (planeX1)
//     + x(t0+1) rows y-1..y+1 (planeX2), all f16, v6 single-copy layout.
//   step1: 12 C-tiles (2 mt x 3 rows x 2 colhalf) -> h^{t0+1} rows y-1..y+1
//     converted to f16 planeB (rows outside [0,64) skipped -> stay zero).
//   step2: 4 tiles x 2 k-halves (k-split, scratch reuses dead planeA) ->
//     h^{t0+2} row y written to global fp32.
// State passes through f16 once per 2 steps (planeB) — absmax budget ok.
// h ping-pongs d_out <-> d_ws; s=31 (odd) writes d_out.

typedef _Float16 half8 __attribute__((ext_vector_type(8)));
typedef float floatx16 __attribute__((ext_vector_type(16)));

#define RSB 136            // bytes per row-block: cols -2..65 as f16
#define BLK 34             // dwords per row-block
#define PA_DW 0            // planeA: h^t,    32 cin x 5 rows (160 blocks)
#define PX1_DW 5440        // planeX1: x(t0),  16 cin x 5 rows (80 blocks)
#define PX2_DW 8160        // planeX2: x(t0+1),16 cin x 3 rows (48 blocks)
#define PB_DW 9792         // planeB: h^{t+1}, 32 cin x 3 rows (96 blocks)
#define BX_DW 13056        // bx staged (96 floats)
#define LDS_DW 13152       // 52.6 KB
#define PA_B (PA_DW * 4)
#define PX1_B (PX1_DW * 4)
#define PX2_B (PX2_DW * 4)
#define PB_B (PB_DW * 4)

static __device__ __forceinline__ unsigned pack2(float a, float b) {
    _Float16 ha = (_Float16)a, hb = (_Float16)b;
    unsigned short ua = *(unsigned short*)&ha, ub = *(unsigned short*)&hb;
    return (unsigned)ua | ((unsigned)ub << 16);
}

static __device__ __forceinline__ float gru_update(float zp, float np, float hp) {
    float z = 1.0f / (1.0f + __expf(-zp));
    float e = __expf(2.0f * np);
    float n = 1.0f - 2.0f / (e + 1.0f);          // tanh, overflow-safe
    return (1.0f - z) * hp + z * n;
}

// byte offset of k-sub-row (chunk c, sub s in 0..3) inside its plane.
// row index in plane = cin*nr + (dy + bias + ky); dyterm = dy*RSB.
static __device__ __forceinline__ int krow_off(int c, int s, int dyterm,
                                               int xbase, int xnr,
                                               int hbase, int hnr, int bias)
{
    int rr = 4 * c + s;
    int off;
    if (rr < 48) { int cin = rr / 3, ky = rr - cin * 3;
                   off = xbase + (cin * xnr + bias + ky) * RSB; }
    else         { int r2 = rr - 48; int cin = r2 / 3, ky = r2 - cin * 3;
                   off = hbase + (cin * hnr + bias + ky) * RSB; }
    return off + dyterm;
}

static __device__ __forceinline__ floatx16 gemm_range(
    const unsigned* plds, const uint4* wfrag,
    int c0, int c1, int mt, int lane, int half, bool par,
    const char* lbase, int dyterm,
    int xbase, int xnr, int hbase, int hnr, int bias, floatx16 acc)
{
#pragma unroll
    for (int c = c0; c < c1; ++c) {
        uint4 aw = wfrag[(size_t)(mt * 36 + c) * 64 + lane];
        int o0 = krow_off(c, 0, dyterm, xbase, xnr, hbase, hnr, bias);
        int o1 = krow_off(c, 1, dyterm, xbase, xnr, hbase, hnr, bias);
        int o2 = krow_off(c, 2, dyterm, xbase, xnr, hbase, hnr, bias);
        int o3 = krow_off(c, 3, dyterm, xbase, xnr, hbase, hnr, bias);
        int offA = half ? o2 : o0;
        int offB = half ? o3 : o1;
        unsigned d0 = *(const unsigned*)(lbase + offA);
        unsigned d1 = *(const unsigned*)(lbase + offA + 4);
        unsigned d2 = *(const unsigned*)(lbase + offA + 8);
        unsigned e0 = *(const unsigned*)(lbase + offB);
        unsigned e1 = *(const unsigned*)(lbase + offB + 4);
        unsigned e2 = *(const unsigned*)(lbase + offB + 8);
        uint4 bf;
        bf.x = par ? d0 : ((d0 >> 16) | (d1 << 16));
        bf.y = par ? d1 : ((d1 >> 16) | (d2 << 16));
        bf.z = par ? e0 : ((e0 >> 16) | (e1 << 16));
        bf.w = par ? e1 : ((e1 >> 16) | (e2 << 16));
        union { uint4 u; half8 h; } ua, ub;
        ua.u = aw; ub.u = bf;
        acc = __builtin_amdgcn_mfma_f32_32x32x16_f16(ua.h, ub.h, acc, 0, 0, 0);
    }
    return acc;
}

// ---- pre-kernel: weights -> A-fragment layout (R6-verified) ----
__global__ __launch_bounds__(64) void build_wfrag(
    const float* __restrict__ Wx, const float* __restrict__ Wh,
    uint4* __restrict__ wfrag)
{
    const int bid   = blockIdx.x;            // 0..71
    const int mtile = bid / 36, chunk = bid % 36;
    const int lane  = threadIdx.x;
    const int m     = lane & 31;
    const int grow  = (m < 16) ? (mtile * 16 + m) : (64 + mtile * 16 + (m - 16));
    unsigned short h[8];
    for (int j = 0; j < 8; ++j) {
        int k   = chunk * 16 + (lane >> 5) * 8 + j;
        int cin = k / 12, t12 = k - cin * 12;
        int p = t12 >> 1, o = t12 & 1;
        int ky = p >> 1, q = p & 1;
        int kx = q ? (2 + o) : o;            // q=1,o=1 -> phantom (w=0)
        float w = 0.0f;
        if (!(q && o)) {
            if (cin < 16) w = Wx[((size_t)grow * 16 + cin) * 9 + ky * 3 + kx];
            else          w = Wh[((size_t)grow * 32 + (cin - 16)) * 9 + ky * 3 + kx];
        }
        _Float16 hw = (_Float16)w;
        h[j] = *(unsigned short*)&hw;
    }
    uint4 o4;
    o4.x = (unsigned)h[0] | ((unsigned)h[1] << 16);
    o4.y = (unsigned)h[2] | ((unsigned)h[3] << 16);
    o4.z = (unsigned)h[4] | ((unsigned)h[5] << 16);
    o4.w = (unsigned)h[6] | ((unsigned)h[7] << 16);
    wfrag[(size_t)bid * 64 + lane] = o4;
}

__global__ __launch_bounds__(512, 1) void convgru_2step(
    const float* __restrict__ x, const float* __restrict__ bx,
    const uint4* __restrict__ wfrag,
    const float* __restrict__ hsrc, float* __restrict__ hdst, int t0)
{
    __shared__ unsigned plds[LDS_DW];
    const int tx = threadIdx.x;
    const int y  = blockIdx.x;               // image row 0..63
    const int b  = blockIdx.y;               // batch 0..3

    // ---- zero planeB + halo dwords (dw0/dw33 of A,X1,X2 blocks) + stage bx ----
#pragma unroll
    for (int i = 0; i < 8; ++i) {
        int z = i * 512 + tx;
        if (z < 3264) plds[PB_DW + z] = 0u;
        else if (z < 3840) {
            int rb = z - 3264;               // 0..575
            int blkid = rb >> 1;             // 0..287 (A,X1,X2 contiguous)
            plds[blkid * BLK + ((rb & 1) ? 33 : 0)] = 0u;
        }
        else if (z < 3936) plds[BX_DW + (z - 3840)] = __float_as_uint(bx[z - 3840]);
    }

    // ---- stage planeA (h^t0, 160 blk), planeX1 (x t0, 80), planeX2 (x t0+1, 48) ----
#pragma unroll
    for (int i = 0; i < 9; ++i) {            // 4608 tasks = 288 blocks x 16 granules
        int task = i * 512 + tx;
        int g = task & 15, idx = task >> 4;
        const float* src; int ys;
        if (idx < 160) {
            int cin = idx / 5, iy = idx - cin * 5;
            ys = y - 2 + iy;
            src = hsrc + (size_t)(b * 32 + cin) * 4096;
        } else if (idx < 240) {
            int r2 = idx - 160; int cin = r2 / 5, iy = r2 - cin * 5;
            ys = y - 2 + iy;
            src = x + ((size_t)(b * 16 + cin) * 64 + t0) * 4096;
        } else {
            int r2 = idx - 240; int cin = r2 / 3, iy = r2 - cin * 3;
            ys = y - 1 + iy;
            src = x + ((size_t)(b * 16 + cin) * 64 + t0 + 1) * 4096;
        }
        float4 v = make_float4(0.f, 0.f, 0.f, 0.f);
        if ((unsigned)ys < 64u) v = *(const float4*)(src + ys * 64 + g * 4);
        // col c at byte 2c+4 within block
        plds[idx * BLK + 2 * g + 1] = pack2(v.x, v.y);
        plds[idx * BLK + 2 * g + 2] = pack2(v.z, v.w);
    }
    __syncthreads();

    const int lane = tx & 63, wv = tx >> 6, half = lane >> 5;

    // ---- step 1: h^{t0+1} rows y-1..y+1 -> planeB (f16) ----
    for (int ti = wv; ti < 12; ti += 8) {
        const int mt  = ti & 1;
        const int dy  = ((ti >> 1) % 3) - 1;
        const int chf = ti / 6;
        const int yp  = y + dy;
        if ((unsigned)yp < 64u) {
            const int xpx = chf * 32 + (lane & 31);
            const bool par = (xpx & 1) != 0;
            const char* lbase = (const char*)plds + ((2 * xpx + 2) & ~3);
            floatx16 acc;
            #pragma unroll
            for (int i2 = 0; i2 < 16; ++i2) acc[i2] = 0.f;
            acc = gemm_range(plds, wfrag, 0, 36, mt, lane, half, par, lbase,
                             dy * RSB, PX1_B, 5, PA_B, 5, 1, acc);
            #pragma unroll
            for (int r = 0; r < 8; ++r) {
                const int row = (r & 3) + 8 * (r >> 2) + 4 * half;
                const int oc  = mt * 16 + row;
                const float bz = __uint_as_float(plds[BX_DW + oc]);
                const float bn = __uint_as_float(plds[BX_DW + 64 + oc]);
                const float hp = hsrc[(size_t)(b * 32 + oc) * 4096 + yp * 64 + xpx];
                float hn = gru_update(acc[r] + bz, acc[r + 8] + bn, hp);
                _Float16 hf = (_Float16)hn;
                *(unsigned short*)((char*)plds + PB_B + (oc * 3 + dy + 1) * RSB
                                   + 2 * xpx + 4) = *(unsigned short*)&hf;
            }
        }
    }
    __syncthreads();

    // ---- step 2: h^{t0+2} row y -> global fp32; k-split over wave pairs ----
    {
        const int kh = wv & 1, tile = wv >> 1;   // 4 tiles x 2 k-halves
        const int mt = tile & 1, chf = tile >> 1;
        const int xpx = chf * 32 + (lane & 31);
        const bool par = (xpx & 1) != 0;
        const char* lbase = (const char*)plds + ((2 * xpx + 2) & ~3);
        floatx16 acc;
        #pragma unroll
        for (int i2 = 0; i2 < 16; ++i2) acc[i2] = 0.f;
        if (kh == 0) {
            acc = gemm_range(plds, wfrag, 0, 18, mt, lane, half, par, lbase,
                             0, PX2_B, 3, PB_B, 3, 0, acc);
        } else {
            acc = gemm_range(plds, wfrag, 18, 36, mt, lane, half, par, lbase,
                             0, PX2_B, 3, PB_B, 3, 0, acc);
            #pragma unroll
            for (int r = 0; r < 16; ++r)     // scratch reuses dead planeA
                plds[PA_DW + tile * 1088 + r * 68 + lane] = __float_as_uint(acc[r]);
        }
        __syncthreads();
        if (kh == 0) {
            #pragma unroll
            for (int r = 0; r < 16; ++r)
                acc[r] += __uint_as_float(plds[PA_DW + tile * 1088 + r * 68 + lane]);
            #pragma unroll
            for (int r = 0; r < 8; ++r) {
                const int row = (r & 3) + 8 * (r >> 2) + 4 * half;
                const int oc  = mt * 16 + row;
                const float bz = __uint_as_float(plds[BX_DW + oc]);
                const float bn = __uint_as_float(plds[BX_DW + 64 + oc]);
                union { unsigned short u; _Float16 f; } hu;
                hu.u = *(const unsigned short*)((const char*)plds + PB_B
                        + (oc * 3 + 1) * RSB + 2 * xpx + 4);
                float hn = gru_update(acc[r] + bz, acc[r + 8] + bn, (float)hu.f);
                hdst[(size_t)(b * 32 + oc) * 4096 + y * 64 + xpx] = hn;
            }
        }
    }
}

extern "C" void kernel_launch(void* const* d_in, const int* in_sizes, int n_in,
                              void* d_out, int out_size, void* d_ws, size_t ws_size,
                              hipStream_t stream) {
    const float* x  = (const float*)d_in[0];
    const float* Wx = (const float*)d_in[1];
    const float* bx = (const float*)d_in[2];
    const float* Wh = (const float*)d_in[3];
    float* out = (float*)d_out;
    float* hws = (float*)d_ws;                               // 2 MB h pong
    uint4* wfrag = (uint4*)((char*)d_ws + (4u << 20));       // 74 KB A-frags

    // h^0 = zeros in d_out. Kernel s: reads h^{2s}, writes h^{2s+2}.
    // s even: out -> hws; s odd: hws -> out; s=31 odd => h^64 lands in d_out.
    hipMemsetAsync(d_out, 0, (size_t)524288 * sizeof(float), stream);
    hipLaunchKernelGGL(build_wfrag, dim3(72), dim3(64), 0, stream, Wx, Wh, wfrag);

    dim3 grid(64, 4), block(512);
    for (int s = 0; s < 32; ++s) {
        const float* src = (s & 1) ? hws : out;
        float*       dst = (s & 1) ? out : hws;
        hipLaunchKernelGGL(convgru_2step, grid, block, 0, stream,
                           x, bx, wfrag, src, dst, 2 * s);
    }
}

// Round 11
// 643.275 us; speedup vs baseline: 1.1347x; 1.1347x over previous
//
#include <hip/hip_runtime.h>
#include <math.h>

// ConvGRU v10: hoisted x-projection + 16x16x32-MFMA h-only step kernels.
// x: (4,16,64,64,64) f32, Wx: (96,16,3,3), bx: (96), Wh: (96,32,3,3).
// r-gate dead: only z rows [0,32) and n rows [64,96).
// K padding: 12 k per cin (9 taps + 3 phantoms), 4 k per (cin,ky) k-row so
// 32-k chunks = 8 k-rows; pairs (2j,2j+1) = adjacent cols in one k-row.
// M: 4 m16-tiles: tile4 = gate*2 + ocg -> rows gate*64 + ocg*16 + m.
// xproj precomputes conv(x,Wx)+bx for all 64 t as f16 in C-frag layout:
//   xp[((t*4+b)*64+y)*8192 + tile4*2048 + px*32 + q*8] = 4 f16 (rows q*4+r).
// Step kernel: stage h^t rows y-1..y+1 (96 k-rows, parity-split f16 copies),
// acc init from xp, 12 chunks x 2 MFMA (z,n share B-frags), gru epilogue.
// h ping-pongs d_out <-> d_ws; t=63 (odd) writes d_out. ws = 256 MiB (measured).

typedef _Float16 half8 __attribute__((ext_vector_type(8)));
typedef float floatx4 __attribute__((ext_vector_type(4)));

#define DWR 37               // dwords per k-row copy (148 B; odd -> 2-way banks)
#define RSB 148
#define CP1H (96 * DWR)      // step: copy1 dword base
#define LDSH (2 * 96 * DWR)  // 7104 dw = 28.4 KB
#define CP1X (48 * DWR)      // xproj: copy1 dword base
#define LDSX (2 * 48 * DWR)  // 3552 dw = 14.2 KB

#define WF_OFF ((size_t)4 << 20)
#define XP_OFF ((size_t)8 << 20)
#define XP_BYTES ((size_t)16384 * 8192)   // (t,b,y) x 8192 B = 134.2 MB

static __device__ __forceinline__ unsigned pack2(float a, float b) {
    _Float16 ha = (_Float16)a, hb = (_Float16)b;
    unsigned short ua = *(unsigned short*)&ha, ub = *(unsigned short*)&hb;
    return (unsigned)ua | ((unsigned)ub << 16);
}

static __device__ __forceinline__ float gru_update(float zp, float np, float hp) {
    float z = 1.0f / (1.0f + __expf(-zp));
    float e = __expf(2.0f * np);
    float n = 1.0f - 2.0f / (e + 1.0f);          // tanh, overflow-safe
    return (1.0f - z) * hp + z * n;
}

// ---- A-fragment builder for 16x16x32: A[m=lane&15][k=(lane>>4)*8+j] ----
// bid 0..47: Wh chunks (tile4*12 + c, K=384); bid 48..71: Wx (48 + tile4*6 + c, K=192)
__global__ __launch_bounds__(64) void build_wf(
    const float* __restrict__ Wx, const float* __restrict__ Wh,
    uint4* __restrict__ wf)
{
    const int bid  = blockIdx.x;
    const int lane = threadIdx.x;
    const int m = lane & 15, q = lane >> 4;
    int tile4, c, wstride; const float* W;
    if (bid < 48) { tile4 = bid / 12; c = bid % 12; W = Wh; wstride = 32; }
    else { int b2 = bid - 48; tile4 = b2 / 6; c = b2 % 6; W = Wx; wstride = 16; }
    const int gate = tile4 >> 1, ocg = tile4 & 1;
    const int grow = gate * 64 + ocg * 16 + m;
    unsigned short h[8];
    for (int j = 0; j < 8; ++j) {
        int k = 32 * c + 8 * q + j;
        int cin = k / 12, t12 = k - cin * 12;
        int p = t12 >> 1, o = t12 & 1;
        int ky = p >> 1, qq = p & 1;
        int kx = qq ? (2 + o) : o;               // qq&&o -> phantom (w=0)
        float w = 0.0f;
        if (!(qq && o)) w = W[((size_t)grow * wstride + cin) * 9 + ky * 3 + kx];
        _Float16 hw = (_Float16)w;
        h[j] = *(unsigned short*)&hw;
    }
    uint4 o4;
    o4.x = (unsigned)h[0] | ((unsigned)h[1] << 16);
    o4.y = (unsigned)h[2] | ((unsigned)h[3] << 16);
    o4.z = (unsigned)h[4] | ((unsigned)h[5] << 16);
    o4.w = (unsigned)h[6] | ((unsigned)h[7] << 16);
    wf[(size_t)bid * 64 + lane] = o4;
}

// ---- xproj: conv(x,Wx)+bx for all t, f16, C-frag layout ----
__global__ __launch_bounds__(512, 2) void xproj_kernel(
    const float* __restrict__ x, const float* __restrict__ bx,
    const uint4* __restrict__ wf, char* __restrict__ xp)
{
    __shared__ unsigned plds[LDSX];
    const int tx = threadIdx.x;
    const int y = blockIdx.x, b = blockIdx.y;
    const int lane = tx & 63, wv = tx >> 6;
    const int ocg = wv & 1, nt = wv >> 1;
    const int col = lane & 15, q = lane >> 4;
    const int px = nt * 16 + col;
    const char* lbase = (const char*)plds
        + ((px & 1) ? (2 * px + 6) : (CP1X * 4 + 2 * px)) + q * (2 * RSB);

    float bz[4], bn[4];
    #pragma unroll
    for (int r = 0; r < 4; ++r) {
        bz[r] = bx[ocg * 16 + q * 4 + r];
        bn[r] = bx[64 + ocg * 16 + q * 4 + r];
    }
    uint4 awz[6], awn[6];
    #pragma unroll
    for (int c = 0; c < 6; ++c) {
        awz[c] = wf[(size_t)(48 + ocg * 6 + c) * 64 + lane];
        awn[c] = wf[(size_t)(48 + (2 + ocg) * 6 + c) * 64 + lane];
    }
    if (tx < 48) plds[tx * DWR + 34] = 0u;       // copy0 right-halo (cols 64,65)

    for (int it = 0; it < 4; ++it) {
        const int t = blockIdx.z * 4 + it;
        __syncthreads();                         // prev reads (or halo zero) done
        #pragma unroll
        for (int i = 0; i < 2; ++i) {            // stage x(t): 768 tasks
            int task = i * 512 + tx;
            if (task < 768) {
                int rr = task >> 4, g = task & 15;
                int cin = rr / 3, ky = rr - cin * 3;
                int ys = y + ky - 1;
                float4 v = make_float4(0.f, 0.f, 0.f, 0.f);
                if ((unsigned)ys < 64u)
                    v = *(const float4*)(x + ((size_t)(b * 16 + cin) * 64 + t) * 4096
                                           + ys * 64 + g * 4);
                float prev = __shfl_up(v.w, 1);
                if (g == 0) prev = 0.f;
                int r37 = rr * DWR;
                plds[r37 + 2 * g + 2] = pack2(v.x, v.y);
                plds[r37 + 2 * g + 3] = pack2(v.z, v.w);
                plds[CP1X + r37 + 2 * g]     = pack2(prev, v.x);
                plds[CP1X + r37 + 2 * g + 1] = pack2(v.y, v.z);
                if (g == 15) plds[CP1X + r37 + 32] = pack2(v.w, 0.f);
            }
        }
        __syncthreads();

        floatx4 az = {0.f, 0.f, 0.f, 0.f}, an = {0.f, 0.f, 0.f, 0.f};
        #pragma unroll
        for (int c = 0; c < 6; ++c) {
            const int B0 = c * 8 * RSB;
            unsigned d0 = *(const unsigned*)(lbase + B0);
            unsigned d1 = *(const unsigned*)(lbase + B0 + 4);
            unsigned e0 = *(const unsigned*)(lbase + B0 + RSB);
            unsigned e1 = *(const unsigned*)(lbase + B0 + RSB + 4);
            uint4 bf; bf.x = d0; bf.y = d1; bf.z = e0; bf.w = e1;
            union { uint4 u; half8 h; } ua, ub, uc;
            ub.u = bf; ua.u = awz[c]; uc.u = awn[c];
            az = __builtin_amdgcn_mfma_f32_16x16x32_f16(ua.h, ub.h, az, 0, 0, 0);
            an = __builtin_amdgcn_mfma_f32_16x16x32_f16(uc.h, ub.h, an, 0, 0, 0);
        }
        const size_t base = ((size_t)((t * 4 + b) * 64 + y)) * 8192 + px * 32 + q * 8;
        uint2 sz, sn;
        sz.x = pack2(az[0] + bz[0], az[1] + bz[1]);
        sz.y = pack2(az[2] + bz[2], az[3] + bz[3]);
        sn.x = pack2(an[0] + bn[0], an[1] + bn[1]);
        sn.y = pack2(an[2] + bn[2], an[3] + bn[3]);
        *(uint2*)(xp + base + ocg * 2048)       = sz;
        *(uint2*)(xp + base + (2 + ocg) * 2048) = sn;
    }
}

// ---- per-timestep kernel: h-conv only ----
__global__ __launch_bounds__(512, 2) void convgru_step16(
    const uint4* __restrict__ wf, const char* __restrict__ xp,
    const float* __restrict__ hsrc, float* __restrict__ hdst, int t)
{
    __shared__ unsigned plds[LDSH];
    const int tx = threadIdx.x;
    const int y = blockIdx.x, b = blockIdx.y;
    const int lane = tx & 63, wv = tx >> 6;
    const int ocg = wv & 1, nt = wv >> 1;
    const int col = lane & 15, q = lane >> 4;
    const int px = nt * 16 + col;

    // preload A-frags + xp init + hprev: all in flight through staging
    uint4 awz[12], awn[12];
    #pragma unroll
    for (int c = 0; c < 12; ++c) {
        awz[c] = wf[(size_t)(ocg * 12 + c) * 64 + lane];
        awn[c] = wf[(size_t)((2 + ocg) * 12 + c) * 64 + lane];
    }
    const size_t xpb = ((size_t)((t * 4 + b) * 64 + y)) * 8192 + px * 32 + q * 8;
    uint2 xz = *(const uint2*)(xp + xpb + ocg * 2048);
    uint2 xn = *(const uint2*)(xp + xpb + (2 + ocg) * 2048);
    float hp[4];
    #pragma unroll
    for (int r = 0; r < 4; ++r)
        hp[r] = hsrc[(size_t)(b * 32 + ocg * 16 + q * 4 + r) * 4096 + y * 64 + px];

    if (tx < 96) plds[tx * DWR + 34] = 0u;       // copy0 right-halo (cols 64,65)
    #pragma unroll
    for (int i = 0; i < 3; ++i) {                // stage h^t: 1536 tasks
        int task = i * 512 + tx;
        int rr = task >> 4, g = task & 15;
        int cin = rr / 3, ky = rr - cin * 3;
        int ys = y + ky - 1;
        float4 v = make_float4(0.f, 0.f, 0.f, 0.f);
        if ((unsigned)ys < 64u)
            v = *(const float4*)(hsrc + (size_t)(b * 32 + cin) * 4096
                                      + ys * 64 + g * 4);
        float prev = __shfl_up(v.w, 1);
        if (g == 0) prev = 0.f;
        int r37 = rr * DWR;
        plds[r37 + 2 * g + 2] = pack2(v.x, v.y);
        plds[r37 + 2 * g + 3] = pack2(v.z, v.w);
        plds[CP1H + r37 + 2 * g]     = pack2(prev, v.x);
        plds[CP1H + r37 + 2 * g + 1] = pack2(v.y, v.z);
        if (g == 15) plds[CP1H + r37 + 32] = pack2(v.w, 0.f);
    }
    __syncthreads();

    const char* lbase = (const char*)plds
        + ((px & 1) ? (2 * px + 6) : (CP1H * 4 + 2 * px)) + q * (2 * RSB);
    union { uint2 u; _Float16 f[4]; } uz, un;
    uz.u = xz; un.u = xn;
    floatx4 az = {(float)uz.f[0], (float)uz.f[1], (float)uz.f[2], (float)uz.f[3]};
    floatx4 an = {(float)un.f[0], (float)un.f[1], (float)un.f[2], (float)un.f[3]};

    #pragma unroll
    for (int c = 0; c < 12; ++c) {
        const int B0 = c * 8 * RSB;              // static immediates
        unsigned d0 = *(const unsigned*)(lbase + B0);
        unsigned d1 = *(const unsigned*)(lbase + B0 + 4);
        unsigned e0 = *(const unsigned*)(lbase + B0 + RSB);
        unsigned e1 = *(const unsigned*)(lbase + B0 + RSB + 4);
        uint4 bf; bf.x = d0; bf.y = d1; bf.z = e0; bf.w = e1;
        union { uint4 u; half8 h; } ua, ub, uc;
        ub.u = bf; ua.u = awz[c]; uc.u = awn[c];
        az = __builtin_amdgcn_mfma_f32_16x16x32_f16(ua.h, ub.h, az, 0, 0, 0);
        an = __builtin_amdgcn_mfma_f32_16x16x32_f16(uc.h, ub.h, an, 0, 0, 0);
    }

    #pragma unroll
    for (int r = 0; r < 4; ++r) {
        const int oc = ocg * 16 + q * 4 + r;
        hdst[(size_t)(b * 32 + oc) * 4096 + y * 64 + px]
            = gru_update(az[r], an[r], hp[r]);
    }
}

extern "C" void kernel_launch(void* const* d_in, const int* in_sizes, int n_in,
                              void* d_out, int out_size, void* d_ws, size_t ws_size,
                              hipStream_t stream) {
    const float* x  = (const float*)d_in[0];
    const float* Wx = (const float*)d_in[1];
    const float* bx = (const float*)d_in[2];
    const float* Wh = (const float*)d_in[3];
    float* out = (float*)d_out;
    float* hws = (float*)d_ws;                          // 2 MB h pong
    uint4* wf  = (uint4*)((char*)d_ws + WF_OFF);        // 72 KB A-frags
    char*  xp  = (char*)d_ws + XP_OFF;                  // 134 MB x_proj (f16)

    // h0 = zeros in d_out (even t: out -> hws; odd t: hws -> out; t=63 -> d_out)
    hipMemsetAsync(d_out, 0, (size_t)524288 * sizeof(float), stream);
    hipLaunchKernelGGL(build_wf, dim3(72), dim3(64), 0, stream, Wx, Wh, wf);
    hipLaunchKernelGGL(xproj_kernel, dim3(64, 4, 16), dim3(512), 0, stream,
                       x, bx, wf, xp);

    dim3 grid(64, 4), block(512);
    for (int t = 0; t < 64; ++t) {
        const float* src = (t & 1) ? hws : out;
        float*       dst = (t & 1) ? out : hws;
        hipLaunchKernelGGL(convgru_step16, grid, block, 0, stream,
                           wf, xp, src, dst, t);
    }
}